// Round 4
// baseline (262.978 us; speedup 1.0000x reference)
//
#include <hip/hip_runtime.h>
#include <hip/hip_bf16.h>

#define C_DIM 384
#define H_NUM 6
#define HS    64
#define B_DIM 128
#define T_DIM 256
#define NROWS (B_DIM * T_DIM)  // 32768

typedef unsigned short u16;
typedef unsigned int u32;
typedef short bf16x8 __attribute__((ext_vector_type(8)));
typedef float floatx4 __attribute__((ext_vector_type(4)));

__device__ __forceinline__ u16 f2b(float f) {
  __hip_bfloat16 h = __float2bfloat16(f);
  u16 u;
  __builtin_memcpy(&u, &h, 2);
  return u;
}
// async global->LDS, 16B per lane. LDS dest is wave-uniform base + lane*16.
__device__ __forceinline__ void gload_lds16(const void* g, void* lds) {
  __builtin_amdgcn_global_load_lds(
      (const __attribute__((address_space(1))) u32*)g,
      (__attribute__((address_space(3))) u32*)lds, 16, 0, 0);
}

// ---------------------------------------------------------------------------
// Prep: weights -> bf16.
// Wh  [h][192][384]: rows = [Wq_h^T(64); Wk_h^T(64); Wv_h^T(64)] (contiguous
//     per head, so fused-kernel B staging is one dense slab).
// Wpt [n=384][c=384] for proj.
// ---------------------------------------------------------------------------
__global__ void cvt_w_kernel(const float* __restrict__ Wq,
                             const float* __restrict__ Wk,
                             const float* __restrict__ Wv,
                             const float* __restrict__ Wp,
                             u16* __restrict__ Wh, u16* __restrict__ Wpt) {
  const int WHN = H_NUM * 192 * C_DIM;  // 442368
  int idx = blockIdx.x * blockDim.x + threadIdx.x;
  if (idx < WHN) {
    int h = idx / (192 * C_DIM);
    int rem = idx % (192 * C_DIM);
    int r = rem / C_DIM, c = rem % C_DIM;
    int tz = r >> 6, d = r & 63;
    const float* W = (tz == 0) ? Wq : (tz == 1) ? Wk : Wv;
    Wh[idx] = f2b(W[((size_t)h * C_DIM + c) * HS + d]);
  } else {
    int j = idx - WHN;
    if (j < C_DIM * C_DIM) {
      int n = j / C_DIM, c = j % C_DIM;
      Wpt[j] = f2b(Wp[c * C_DIM + n]);
    }
  }
}

// ---------------------------------------------------------------------------
// Attention chunk (round-3 verified): QK^T -> masked exp -> P via LDS -> PV.
// ---------------------------------------------------------------------------
template <bool DIAG>
__device__ __forceinline__ void attn_chunk(int c, int mt, int lane, int ln,
                                           int qd, const bf16x8* qf,
                                           const u16* Kls, u16* Pw,
                                           const u16* vTg, floatx4* oacc,
                                           float* lsum) {
  floatx4 sacc[4];
#pragma unroll
  for (int st = 0; st < 4; ++st) {
    sacc[st] = floatx4{0.f, 0.f, 0.f, 0.f};
#pragma unroll
    for (int kc = 0; kc < 2; ++kc) {
      bf16x8 kf = *(const bf16x8*)&Kls[((c * 4 + st) * 2 + kc) * 512 + lane * 8];
      sacc[st] =
          __builtin_amdgcn_mfma_f32_16x16x32_bf16(qf[kc], kf, sacc[st], 0, 0, 0);
    }
  }
#pragma unroll
  for (int st = 0; st < 4; ++st) {
#pragma unroll
    for (int r = 0; r < 4; ++r) {
      const float sv = sacc[st][r] * 0.125f;
      float p = __expf(sv);
      if (DIAG) {
        const bool ok = (c * 64 + st * 16 + ln) <= (mt * 16 + qd * 4 + r);
        p = ok ? p : 0.f;
      }
      lsum[r] += p;
      Pw[(qd * 4 + r) * 72 + st * 16 + ln] = f2b(p);
    }
  }
#pragma unroll
  for (int kc2 = 0; kc2 < 2; ++kc2) {
    bf16x8 pf = *(const bf16x8*)&Pw[ln * 72 + kc2 * 32 + qd * 8];
#pragma unroll
    for (int dt = 0; dt < 4; ++dt) {
      bf16x8 vf = *(const bf16x8*)(vTg + (dt * 16 + ln) * 256 + c * 64 +
                                   kc2 * 32 + qd * 8);
      oacc[dt] =
          __builtin_amdgcn_mfma_f32_16x16x32_bf16(pf, vf, oacc[dt], 0, 0, 0);
    }
  }
}

// ---------------------------------------------------------------------------
// FUSED kernel: per (b,h) block, 512 threads (8 waves).
// Phase 1 (GEMM1): [256 t-rows] x [192 cols = q|k|v of this head], K=384,
//   reading x fp32 directly (cvt during staging). q/k -> per-block global
//   scratch [t][d]; v -> LDS transpose -> coalesced vT [d][t] scratch.
//   Scratch is written+read by the SAME block -> L1/L2-local, no inter-kernel
//   HBM round trip.
// Phase 2 (attn): round-3 verified MFMA flash attention, 8 waves,
//   wave w owns m-tiles {w, 15-w} (balanced: 5 chunk-iters each).
// LDS: phase-aliased union, peak 51200 B -> 3 blocks/CU by LDS.
// ---------------------------------------------------------------------------
__global__ __launch_bounds__(512, 4) void qkv_attn(
    const float* __restrict__ x, const u16* __restrict__ Wh,
    u16* __restrict__ qsA, u16* __restrict__ ksA, u16* __restrict__ vtA,
    u16* __restrict__ y) {
  __shared__ u16 smem[25600];  // 51200 B
  const int bh = blockIdx.x;
  const int b = bh / H_NUM, h = bh % H_NUM;
  const int tid = threadIdx.x, lane = tid & 63, w = tid >> 6;
  const int qd = lane >> 4, ln = lane & 15;
  const int wm = w & 1, wn = w >> 1;
  const int lr = lane >> 3, lkc = (lane & 7) * 8;

  const float* xb = x + (size_t)b * T_DIM * C_DIM;
  const u16* Bh = Wh + (size_t)h * 192 * C_DIM;
  u16* qs = qsA + (size_t)bh * (T_DIM * HS);
  u16* ks = ksA + (size_t)bh * (T_DIM * HS);
  u16* vt = vtA + (size_t)bh * (T_DIM * HS);

  u16* As = smem;            // [128][64]  (8192)
  u16* Bs = smem + 8192;     // [192][64]  (12288)
  u16* Ts = smem;            // v-transpose scratch [64][136] (8704), aliases As

  // ---------------- Phase 1: GEMM1 ----------------
  for (int mh = 0; mh < 2; ++mh) {
    const int t0 = mh * 128;
    floatx4 acc[4][3];
#pragma unroll
    for (int mt = 0; mt < 4; ++mt)
#pragma unroll
      for (int nt = 0; nt < 3; ++nt) acc[mt][nt] = floatx4{0.f, 0.f, 0.f, 0.f};

    for (int kb = 0; kb < 6; ++kb) {
      const int k0 = kb * 64;
      __syncthreads();
      // A: x fp32 -> bf16 -> LDS. 1024 8-elem chunks / 512 threads.
#pragma unroll
      for (int s = 0; s < 2; ++s) {
        const int c = s * 512 + tid;
        const int row = c >> 3, col = (c & 7) * 8;
        const float* src = xb + (size_t)(t0 + row) * C_DIM + k0 + col;
        const float4 f0 = *(const float4*)src;
        const float4 f1 = *(const float4*)(src + 4);
        bf16x8 pk;
        pk[0] = (short)f2b(f0.x); pk[1] = (short)f2b(f0.y);
        pk[2] = (short)f2b(f0.z); pk[3] = (short)f2b(f0.w);
        pk[4] = (short)f2b(f1.x); pk[5] = (short)f2b(f1.y);
        pk[6] = (short)f2b(f1.z); pk[7] = (short)f2b(f1.w);
        *(bf16x8*)&As[row * 64 + col] = pk;
      }
      // B: async 16B, 24 strips of 8 rows / 8 waves = 3 per wave.
#pragma unroll
      for (int ss = 0; ss < 3; ++ss) {
        const int rbase = (w * 3 + ss) * 8;
        gload_lds16(Bh + (size_t)(rbase + lr) * C_DIM + k0 + lkc,
                    Bs + rbase * 64);
      }
      __syncthreads();
#pragma unroll
      for (int kk = 0; kk < 2; ++kk) {
        bf16x8 af[4], bfr[3];
#pragma unroll
        for (int mt = 0; mt < 4; ++mt)
          af[mt] =
              *(const bf16x8*)&As[(wm * 64 + mt * 16 + ln) * 64 + kk * 32 + qd * 8];
#pragma unroll
        for (int nt = 0; nt < 3; ++nt)
          bfr[nt] =
              *(const bf16x8*)&Bs[(wn * 48 + nt * 16 + ln) * 64 + kk * 32 + qd * 8];
#pragma unroll
        for (int mt = 0; mt < 4; ++mt)
#pragma unroll
          for (int nt = 0; nt < 3; ++nt)
            acc[mt][nt] = __builtin_amdgcn_mfma_f32_16x16x32_bf16(
                af[mt], bfr[nt], acc[mt][nt], 0, 0, 0);
      }
    }
    __syncthreads();  // As reads done; Ts (alias) safe to write
    // Epilogue: q/k -> global scratch [t][d]; v -> Ts [d][136-stride].
    // tz is wave-uniform per nt (16-col tile never straddles a 64 boundary).
#pragma unroll
    for (int nt = 0; nt < 3; ++nt) {
      const int tz = (wn * 48 + nt * 16) >> 6;
      const int d = (wn * 48 + nt * 16 + ln) & 63;
#pragma unroll
      for (int mt = 0; mt < 4; ++mt) {
#pragma unroll
        for (int r = 0; r < 4; ++r) {
          const int tl = wm * 64 + mt * 16 + qd * 4 + r;  // 0..127
          const u16 val = f2b(acc[mt][nt][r]);
          if (tz == 0) qs[(size_t)(t0 + tl) * HS + d] = val;
          else if (tz == 1) ks[(size_t)(t0 + tl) * HS + d] = val;
          else Ts[d * 136 + tl] = val;  // stride 136: 2-way banks (free), 16B-aligned rows
        }
      }
    }
    __syncthreads();
    // vT copy-out, coalesced 16B: vt[d][t0..t0+128)
#pragma unroll
    for (int s = 0; s < 2; ++s) {
      const int c = s * 512 + tid;
      const int d = c >> 4, part = c & 15;
      *(uint4*)&vt[(size_t)d * T_DIM + t0 + part * 8] =
          *(const uint4*)&Ts[d * 136 + part * 8];
    }
  }
  __syncthreads();  // scratch complete; LDS free for attn

  // ---------------- Phase 2: attention ----------------
  u16* Kls = smem;                       // 32 frags * 512 = 16384 (32 KB)
  u16* Pw = smem + 16384 + w * 1152;     // per-wave P [16][72]

  // K fragments: 32 frags / 8 waves = 4 each (async 16B)
#pragma unroll
  for (int ff = 0; ff < 4; ++ff) {
    const int fid = w * 4 + ff, S16 = fid >> 1, kc = fid & 1;
    gload_lds16(ks + (S16 * 16 + ln) * HS + kc * 32 + qd * 8, &Kls[fid * 512]);
  }
  __syncthreads();

#pragma unroll
  for (int i = 0; i < 2; ++i) {
    const int mt = (i == 0) ? w : 15 - w;  // balanced causal split
    bf16x8 qf[2];
#pragma unroll
    for (int kc = 0; kc < 2; ++kc)
      qf[kc] = *(const bf16x8*)(qs + (mt * 16 + ln) * HS + kc * 32 + qd * 8);

    floatx4 oacc[4];
    float lsum[4];
#pragma unroll
    for (int dt = 0; dt < 4; ++dt) oacc[dt] = floatx4{0.f, 0.f, 0.f, 0.f};
#pragma unroll
    for (int r = 0; r < 4; ++r) lsum[r] = 0.f;

    const int cmax = mt >> 2;
    for (int c = 0; c < cmax; ++c)
      attn_chunk<false>(c, mt, lane, ln, qd, qf, Kls, Pw, vt, oacc, lsum);
    attn_chunk<true>(cmax, mt, lane, ln, qd, qf, Kls, Pw, vt, oacc, lsum);

#pragma unroll
    for (int off = 1; off < 16; off <<= 1)
#pragma unroll
      for (int r = 0; r < 4; ++r) lsum[r] += __shfl_xor(lsum[r], off);

#pragma unroll
    for (int r = 0; r < 4; ++r) {
      const float inv = 1.f / lsum[r];
      const int t = mt * 16 + qd * 4 + r;
      u16* yo = y + ((size_t)b * T_DIM + t) * C_DIM + h * HS;
#pragma unroll
      for (int dt = 0; dt < 4; ++dt) yo[dt * 16 + ln] = f2b(oacc[dt][r] * inv);
    }
  }
}

// ---------------------------------------------------------------------------
// MFMA GEMM core (m97 pattern) for the output projection.
// ---------------------------------------------------------------------------
struct GemmAcc {
  floatx4 acc[4][4];
};

__device__ __forceinline__ void gemm_tile_128x128(
    const u16* __restrict__ a_rows, const u16* __restrict__ bt_rows,
    u16* As, u16* Bs, GemmAcc& g) {
  const int tid = threadIdx.x;
  const int lane = tid & 63;
  const int w = tid >> 6;
  const int lr = lane >> 3;
  const int lkc = (lane & 7) * 8;
  const int qd = lane >> 4;
  const int ln = lane & 15;
  const int mw = (w >> 1) * 64;
  const int nw = (w & 1) * 64;

#pragma unroll
  for (int i = 0; i < 4; ++i)
#pragma unroll
    for (int j = 0; j < 4; ++j) g.acc[i][j] = floatx4{0.f, 0.f, 0.f, 0.f};

  for (int kb = 0; kb < C_DIM / 64; ++kb) {
    const int k0 = kb * 64;
    __syncthreads();
#pragma unroll
    for (int s = 0; s < 4; ++s) {
      const int rbase = (s * 4 + w) * 8;
      gload_lds16(a_rows + (size_t)(rbase + lr) * C_DIM + k0 + lkc,
                  As + rbase * 64);
      gload_lds16(bt_rows + (size_t)(rbase + lr) * C_DIM + k0 + lkc,
                  Bs + rbase * 64);
    }
    __syncthreads();

#pragma unroll
    for (int kk = 0; kk < 2; ++kk) {
      bf16x8 af[4], bf[4];
#pragma unroll
      for (int mt = 0; mt < 4; ++mt)
        af[mt] = *(const bf16x8*)&As[(mw + mt * 16 + ln) * 64 + kk * 32 + qd * 8];
#pragma unroll
      for (int nt = 0; nt < 4; ++nt)
        bf[nt] = *(const bf16x8*)&Bs[(nw + nt * 16 + ln) * 64 + kk * 32 + qd * 8];
#pragma unroll
      for (int mt = 0; mt < 4; ++mt)
#pragma unroll
        for (int nt = 0; nt < 4; ++nt)
          g.acc[mt][nt] = __builtin_amdgcn_mfma_f32_16x16x32_bf16(
              af[mt], bf[nt], g.acc[mt][nt], 0, 0, 0);
    }
  }
}

// ---------------------------------------------------------------------------
// Output projection via MFMA.
// ---------------------------------------------------------------------------
__global__ __launch_bounds__(256) void proj_gemm(
    const u16* __restrict__ yb, const u16* __restrict__ Wpt,
    const float* __restrict__ bp, float* __restrict__ out) {
  __shared__ u16 As[128 * 64];
  __shared__ u16 Bs[128 * 64];
  const int row0 = blockIdx.x * 128;
  const int n0 = blockIdx.y * 128;

  GemmAcc g;
  gemm_tile_128x128(yb + (size_t)row0 * C_DIM, Wpt + (size_t)n0 * C_DIM, As, Bs, g);

  const int lane = threadIdx.x & 63;
  const int w = threadIdx.x >> 6;
  const int qd = lane >> 4, ln = lane & 15;
  const int mw = (w >> 1) * 64, nw = (w & 1) * 64;
#pragma unroll
  for (int nt = 0; nt < 4; ++nt) {
    const int col = n0 + nw + nt * 16 + ln;
    const float bias = bp[col];
#pragma unroll
    for (int mt = 0; mt < 4; ++mt) {
#pragma unroll
      for (int r = 0; r < 4; ++r) {
        const int grow = row0 + mw + mt * 16 + qd * 4 + r;
        out[(size_t)grow * C_DIM + col] = g.acc[mt][nt][r] + bias;
      }
    }
  }
}

// ---------------------------------------------------------------------------
extern "C" void kernel_launch(void* const* d_in, const int* in_sizes, int n_in,
                              void* d_out, int out_size, void* d_ws, size_t ws_size,
                              hipStream_t stream) {
  const float* x  = (const float*)d_in[0];
  const float* Wq = (const float*)d_in[1];
  const float* Wk = (const float*)d_in[2];
  const float* Wv = (const float*)d_in[3];
  const float* Wp = (const float*)d_in[4];
  const float* bp = (const float*)d_in[5];
  float* out = (float*)d_out;

  const size_t qkv_elems = (size_t)B_DIM * H_NUM * T_DIM * HS;  // 12,582,912

  u16* Wh  = (u16*)d_ws;                   //   442368
  u16* Wpt = Wh + (size_t)H_NUM * 192 * C_DIM;
  u16* qsA = Wpt + C_DIM * C_DIM;          // per-(b,h) scratch [t][d]
  u16* ksA = qsA + qkv_elems;
  u16* vtA = ksA + qkv_elems;              // [d][t]
  u16* y   = vtA + qkv_elems;              // [b][t][384] bf16
  // total ws: ~101.8 MB

  cvt_w_kernel<<<2304, 256, 0, stream>>>(Wq, Wk, Wv, Wp, Wh, Wpt);
  qkv_attn<<<B_DIM * H_NUM, 512, 0, stream>>>(x, Wh, qsA, ksA, vtA, y);
  proj_gemm<<<dim3(NROWS / 128, 3), 256, 0, stream>>>(y, Wpt, bp, out);
}

// Round 5
// 237.192 us; speedup vs baseline: 1.1087x; 1.1087x over previous
//
#include <hip/hip_runtime.h>
#include <hip/hip_bf16.h>

#define C_DIM 384
#define H_NUM 6
#define HS    64
#define B_DIM 128
#define T_DIM 256
#define NROWS (B_DIM * T_DIM)  // 32768

typedef unsigned short u16;
typedef unsigned int u32;
typedef short bf16x8 __attribute__((ext_vector_type(8)));
typedef float floatx4 __attribute__((ext_vector_type(4)));

__device__ __forceinline__ float b2f(u16 u) {
  u32 i = ((u32)u) << 16;
  float f;
  __builtin_memcpy(&f, &i, 4);
  return f;
}
__device__ __forceinline__ u16 f2b(float f) {
  __hip_bfloat16 h = __float2bfloat16(f);
  u16 u;
  __builtin_memcpy(&u, &h, 2);
  return u;
}
// async global->LDS, 16B per lane. LDS dest is wave-uniform base + lane*16.
__device__ __forceinline__ void gload_lds16(const void* g, void* lds) {
  __builtin_amdgcn_global_load_lds(
      (const __attribute__((address_space(1))) u32*)g,
      (__attribute__((address_space(3))) u32*)lds, 16, 0, 0);
}

// ---------------------------------------------------------------------------
// Prep: weights -> bf16 transposed. Wt [18][64][384], Wpt [384][384].
// ---------------------------------------------------------------------------
__global__ void cvt_w_kernel(const float* __restrict__ Wq,
                             const float* __restrict__ Wk,
                             const float* __restrict__ Wv,
                             const float* __restrict__ Wp,
                             u16* __restrict__ Wt, u16* __restrict__ Wpt) {
  const int QKV = 3 * H_NUM * HS * C_DIM;  // 442368
  int idx = blockIdx.x * blockDim.x + threadIdx.x;
  if (idx < QKV) {
    int slab = idx / (HS * C_DIM);
    int rem = idx % (HS * C_DIM);
    int d = rem / C_DIM, c = rem % C_DIM;
    int tz = slab / H_NUM, h = slab % H_NUM;
    const float* W = (tz == 0) ? Wq : (tz == 1) ? Wk : Wv;
    Wt[idx] = f2b(W[(h * C_DIM + c) * HS + d]);
  } else {
    int j = idx - QKV;
    if (j < C_DIM * C_DIM) {
      int n = j / C_DIM, c = j % C_DIM;
      Wpt[j] = f2b(Wp[c * C_DIM + n]);
    }
  }
}

// ---------------------------------------------------------------------------
// Kernel A: QKV projection via MFMA, A = x read DIRECTLY as fp32 with inline
// bf16 conversion in the staging loop (no cvt_x kernel, no xb buffer).
// 128x128 tile, BK=64. q,k written [bh][t][d]; V written TRANSPOSED
// vT [bh][d][t] via LDS transpose.
// ---------------------------------------------------------------------------
__global__ __launch_bounds__(256) void qkv_gemm(
    const float* __restrict__ x, const u16* __restrict__ Wt,
    u16* __restrict__ q, u16* __restrict__ k, u16* __restrict__ vT) {
  __shared__ u16 smem[128 * 136];  // 34816 B; first 32 KB doubles as As/Bs
  u16* As = smem;
  u16* Bs = smem + 8192;
  const int row0 = blockIdx.x * 128;
  const int sb = blockIdx.y;
  const int tz = sb / 3;
  const int h0 = (sb % 3) * 2;
  const u16* wbase = Wt + (size_t)(tz * H_NUM + h0) * (HS * C_DIM);
  const float* a_rows = x + (size_t)row0 * C_DIM;

  const int tid = threadIdx.x;
  const int lane = tid & 63;
  const int w = tid >> 6;
  const int lr = lane >> 3;
  const int lkc = (lane & 7) * 8;
  const int qd = lane >> 4;
  const int ln = lane & 15;
  const int mw = (w >> 1) * 64;
  const int nw = (w & 1) * 64;

  floatx4 acc[4][4];
#pragma unroll
  for (int i = 0; i < 4; ++i)
#pragma unroll
    for (int j = 0; j < 4; ++j) acc[i][j] = floatx4{0.f, 0.f, 0.f, 0.f};

  for (int kb = 0; kb < C_DIM / 64; ++kb) {
    const int k0 = kb * 64;
    __syncthreads();
    // A: x fp32 -> bf16 -> LDS. 1024 8-elem chunks / 256 threads = 4 each.
#pragma unroll
    for (int s = 0; s < 4; ++s) {
      const int c = s * 256 + tid;
      const int row = c >> 3, col = (c & 7) * 8;
      const float* src = a_rows + (size_t)row * C_DIM + k0 + col;
      const float4 f0 = *(const float4*)src;
      const float4 f1 = *(const float4*)(src + 4);
      bf16x8 pk;
      pk[0] = (short)f2b(f0.x); pk[1] = (short)f2b(f0.y);
      pk[2] = (short)f2b(f0.z); pk[3] = (short)f2b(f0.w);
      pk[4] = (short)f2b(f1.x); pk[5] = (short)f2b(f1.y);
      pk[6] = (short)f2b(f1.z); pk[7] = (short)f2b(f1.w);
      *(bf16x8*)&As[row * 64 + col] = pk;
    }
    // B: async 16B, 16 strips of 8 rows / 4 waves = 4 per wave.
#pragma unroll
    for (int s = 0; s < 4; ++s) {
      const int rbase = (s * 4 + w) * 8;
      gload_lds16(wbase + (size_t)(rbase + lr) * C_DIM + k0 + lkc,
                  Bs + rbase * 64);
    }
    __syncthreads();

#pragma unroll
    for (int kk = 0; kk < 2; ++kk) {
      bf16x8 af[4], bf[4];
#pragma unroll
      for (int mt = 0; mt < 4; ++mt)
        af[mt] = *(const bf16x8*)&As[(mw + mt * 16 + ln) * 64 + kk * 32 + qd * 8];
#pragma unroll
      for (int nt = 0; nt < 4; ++nt)
        bf[nt] = *(const bf16x8*)&Bs[(nw + nt * 16 + ln) * 64 + kk * 32 + qd * 8];
#pragma unroll
      for (int mt = 0; mt < 4; ++mt)
#pragma unroll
        for (int nt = 0; nt < 4; ++nt)
          acc[mt][nt] = __builtin_amdgcn_mfma_f32_16x16x32_bf16(
              af[mt], bf[nt], acc[mt][nt], 0, 0, 0);
    }
  }

  if (tz < 2) {
    u16* outbase = (tz == 0) ? q : k;
#pragma unroll
    for (int mt = 0; mt < 4; ++mt) {
#pragma unroll
      for (int nt = 0; nt < 4; ++nt) {
        const int cl = nw + nt * 16 + ln;
        const int head = h0 + (cl >> 6), d = cl & 63;
#pragma unroll
        for (int r = 0; r < 4; ++r) {
          const int grow = row0 + mw + mt * 16 + qd * 4 + r;
          const int b = grow >> 8, t = grow & 255;
          outbase[(((size_t)b * H_NUM + head) * T_DIM + t) * HS + d] =
              f2b(acc[mt][nt][r]);
        }
      }
    }
  } else {
    // V: transpose 128(t) x 128(d) tile in LDS (row stride 136 -> 2-way banks)
    __syncthreads();  // all waves done reading As/Bs
#pragma unroll
    for (int mt = 0; mt < 4; ++mt)
#pragma unroll
      for (int nt = 0; nt < 4; ++nt)
#pragma unroll
        for (int r = 0; r < 4; ++r)
          smem[(nw + nt * 16 + ln) * 136 + mw + mt * 16 + qd * 4 + r] =
              f2b(acc[mt][nt][r]);
    __syncthreads();
    const int b = row0 >> 8;
    const int t0 = row0 & 255;
#pragma unroll
    for (int it = 0; it < 8; ++it) {
      const int idx = it * 256 + tid;
      const int d_l = idx >> 4, tc = idx & 15;
      uint4 val = *(const uint4*)&smem[d_l * 136 + tc * 8];
      const int head = h0 + (d_l >> 6), d = d_l & 63;
      *(uint4*)&vT[(((size_t)b * H_NUM + head) * HS + d) * T_DIM + t0 + tc * 8] =
          val;
    }
  }
}

// ---------------------------------------------------------------------------
// Kernel B: MFMA flash attention (round-3 verified, unchanged).
// ---------------------------------------------------------------------------
template <bool DIAG>
__device__ __forceinline__ void attn_chunk(int c, int mt, int lane, int ln,
                                           int qd, const bf16x8* qf,
                                           const u16* Kls, u16* Pw,
                                           const u16* vTg, floatx4* oacc,
                                           float* lsum) {
  floatx4 sacc[4];
#pragma unroll
  for (int st = 0; st < 4; ++st) {
    sacc[st] = floatx4{0.f, 0.f, 0.f, 0.f};
#pragma unroll
    for (int kc = 0; kc < 2; ++kc) {
      bf16x8 kf = *(const bf16x8*)&Kls[((c * 4 + st) * 2 + kc) * 512 + lane * 8];
      sacc[st] =
          __builtin_amdgcn_mfma_f32_16x16x32_bf16(qf[kc], kf, sacc[st], 0, 0, 0);
    }
  }
#pragma unroll
  for (int st = 0; st < 4; ++st) {
#pragma unroll
    for (int r = 0; r < 4; ++r) {
      const float sv = sacc[st][r] * 0.125f;
      float p = __expf(sv);
      if (DIAG) {
        const bool ok = (c * 64 + st * 16 + ln) <= (mt * 16 + qd * 4 + r);
        p = ok ? p : 0.f;
      }
      lsum[r] += p;
      Pw[(qd * 4 + r) * 72 + st * 16 + ln] = f2b(p);
    }
  }
#pragma unroll
  for (int kc2 = 0; kc2 < 2; ++kc2) {
    bf16x8 pf = *(const bf16x8*)&Pw[ln * 72 + kc2 * 32 + qd * 8];
#pragma unroll
    for (int dt = 0; dt < 4; ++dt) {
      bf16x8 vf = *(const bf16x8*)(vTg + (dt * 16 + ln) * 256 + c * 64 +
                                   kc2 * 32 + qd * 8);
      oacc[dt] =
          __builtin_amdgcn_mfma_f32_16x16x32_bf16(pf, vf, oacc[dt], 0, 0, 0);
    }
  }
}

__global__ __launch_bounds__(256) void attn_mfma(
    const u16* __restrict__ q, const u16* __restrict__ k,
    const u16* __restrict__ vT, u16* __restrict__ y) {
  __shared__ u16 Kls[32 * 512];   // 32 KB, fragment-major
  __shared__ u16 Pls[4 * 1152];   // per-wave P [16][72] bf16
  const int bh = blockIdx.x;
  const int b = bh / H_NUM, h = bh % H_NUM;
  const int tid = threadIdx.x, lane = tid & 63, w = tid >> 6;
  const int ln = lane & 15, qd = lane >> 4;
  const u16* qg = q + (size_t)bh * (T_DIM * HS);
  const u16* kg = k + (size_t)bh * (T_DIM * HS);
  const u16* vTg = vT + (size_t)bh * (HS * T_DIM);
  u16* Pw = Pls + w * 1152;

#pragma unroll
  for (int ff = 0; ff < 8; ++ff) {
    const int fid = w * 8 + ff;
    const int S16 = fid >> 1, kc = fid & 1;
    gload_lds16(kg + (S16 * 16 + ln) * 64 + kc * 32 + qd * 8, &Kls[fid * 512]);
  }
  __syncthreads();

#pragma unroll
  for (int i = 0; i < 4; ++i) {
    const int mt = i * 4 + w;
    bf16x8 qf[2];
#pragma unroll
    for (int kc = 0; kc < 2; ++kc)
      qf[kc] = *(const bf16x8*)(qg + (mt * 16 + ln) * 64 + kc * 32 + qd * 8);

    floatx4 oacc[4];
    float lsum[4];
#pragma unroll
    for (int dt = 0; dt < 4; ++dt) oacc[dt] = floatx4{0.f, 0.f, 0.f, 0.f};
#pragma unroll
    for (int r = 0; r < 4; ++r) lsum[r] = 0.f;

    const int cmax = mt >> 2;
    for (int c = 0; c < cmax; ++c)
      attn_chunk<false>(c, mt, lane, ln, qd, qf, Kls, Pw, vTg, oacc, lsum);
    attn_chunk<true>(cmax, mt, lane, ln, qd, qf, Kls, Pw, vTg, oacc, lsum);

#pragma unroll
    for (int off = 1; off < 16; off <<= 1)
#pragma unroll
      for (int r = 0; r < 4; ++r) lsum[r] += __shfl_xor(lsum[r], off);

#pragma unroll
    for (int r = 0; r < 4; ++r) {
      const float inv = 1.f / lsum[r];
      const int t = mt * 16 + qd * 4 + r;
      u16* yo = y + ((size_t)b * T_DIM + t) * C_DIM + h * HS;
#pragma unroll
      for (int dt = 0; dt < 4; ++dt) yo[dt * 16 + ln] = f2b(oacc[dt][r] * inv);
    }
  }
}

// ---------------------------------------------------------------------------
// Kernel C: output projection via MFMA (round-3 verified, unchanged).
// ---------------------------------------------------------------------------
__global__ __launch_bounds__(256) void proj_gemm(
    const u16* __restrict__ yb, const u16* __restrict__ Wpt,
    const float* __restrict__ bp, float* __restrict__ out) {
  __shared__ u16 As[128 * 64];
  __shared__ u16 Bs[128 * 64];
  const int row0 = blockIdx.x * 128;
  const int n0 = blockIdx.y * 128;
  const u16* a_rows = yb + (size_t)row0 * C_DIM;
  const u16* bt_rows = Wpt + (size_t)n0 * C_DIM;

  const int tid = threadIdx.x;
  const int lane = tid & 63;
  const int w = tid >> 6;
  const int lr = lane >> 3;
  const int lkc = (lane & 7) * 8;
  const int qd = lane >> 4;
  const int ln = lane & 15;
  const int mw = (w >> 1) * 64;
  const int nw = (w & 1) * 64;

  floatx4 acc[4][4];
#pragma unroll
  for (int i = 0; i < 4; ++i)
#pragma unroll
    for (int j = 0; j < 4; ++j) acc[i][j] = floatx4{0.f, 0.f, 0.f, 0.f};

  for (int kb = 0; kb < C_DIM / 64; ++kb) {
    const int k0 = kb * 64;
    __syncthreads();
#pragma unroll
    for (int s = 0; s < 4; ++s) {
      const int rbase = (s * 4 + w) * 8;
      gload_lds16(a_rows + (size_t)(rbase + lr) * C_DIM + k0 + lkc,
                  As + rbase * 64);
      gload_lds16(bt_rows + (size_t)(rbase + lr) * C_DIM + k0 + lkc,
                  Bs + rbase * 64);
    }
    __syncthreads();

#pragma unroll
    for (int kk = 0; kk < 2; ++kk) {
      bf16x8 af[4], bf[4];
#pragma unroll
      for (int mt = 0; mt < 4; ++mt)
        af[mt] = *(const bf16x8*)&As[(mw + mt * 16 + ln) * 64 + kk * 32 + qd * 8];
#pragma unroll
      for (int nt = 0; nt < 4; ++nt)
        bf[nt] = *(const bf16x8*)&Bs[(nw + nt * 16 + ln) * 64 + kk * 32 + qd * 8];
#pragma unroll
      for (int mt = 0; mt < 4; ++mt)
#pragma unroll
        for (int nt = 0; nt < 4; ++nt)
          acc[mt][nt] = __builtin_amdgcn_mfma_f32_16x16x32_bf16(
              af[mt], bf[nt], acc[mt][nt], 0, 0, 0);
    }
  }

#pragma unroll
  for (int nt = 0; nt < 4; ++nt) {
    const int col = n0 + nw + nt * 16 + ln;
    const float bias = bp[col];
#pragma unroll
    for (int mt = 0; mt < 4; ++mt) {
#pragma unroll
      for (int r = 0; r < 4; ++r) {
        const int grow = row0 + mw + mt * 16 + qd * 4 + r;
        out[(size_t)grow * C_DIM + col] = acc[mt][nt][r] + bias;
      }
    }
  }
}

// ---------------------------------------------------------------------------
extern "C" void kernel_launch(void* const* d_in, const int* in_sizes, int n_in,
                              void* d_out, int out_size, void* d_ws, size_t ws_size,
                              hipStream_t stream) {
  const float* x  = (const float*)d_in[0];
  const float* Wq = (const float*)d_in[1];
  const float* Wk = (const float*)d_in[2];
  const float* Wv = (const float*)d_in[3];
  const float* Wp = (const float*)d_in[4];
  const float* bp = (const float*)d_in[5];
  float* out = (float*)d_out;

  const size_t qkv_elems = (size_t)B_DIM * H_NUM * T_DIM * HS;  // 12,582,912

  u16* Wt  = (u16*)d_ws;                    // [18][64][384]
  u16* Wpt = Wt + 3 * H_NUM * HS * C_DIM;   // [384][384]
  u16* q   = Wpt + C_DIM * C_DIM;           // [bh][t][d]
  u16* k   = q + qkv_elems;                 // [bh][t][d]
  u16* vT  = k + qkv_elems;                 // [bh][d][t]
  u16* y   = vT + qkv_elems;                // [b][t][384] bf16
  // ws: ~1.2 + 75.5 + 25.2 = ~102 MB

  cvt_w_kernel<<<2304, 256, 0, stream>>>(Wq, Wk, Wv, Wp, Wt, Wpt);
  qkv_gemm<<<dim3(NROWS / 128, 9), 256, 0, stream>>>(x, Wt, q, k, vT);
  attn_mfma<<<B_DIM * H_NUM, 256, 0, stream>>>(q, k, vT, y);
  proj_gemm<<<dim3(NROWS / 128, 3), 256, 0, stream>>>(y, Wpt, bp, out);
}

// Round 6
// 223.206 us; speedup vs baseline: 1.1782x; 1.0627x over previous
//
#include <hip/hip_runtime.h>
#include <hip/hip_bf16.h>

#define C_DIM 384
#define H_NUM 6
#define HS    64
#define B_DIM 128
#define T_DIM 256
#define NROWS (B_DIM * T_DIM)  // 32768

typedef unsigned short u16;
typedef unsigned int u32;
typedef short bf16x8 __attribute__((ext_vector_type(8)));
typedef float floatx4 __attribute__((ext_vector_type(4)));

__device__ __forceinline__ u16 f2b(float f) {
  __hip_bfloat16 h = __float2bfloat16(f);
  u16 u;
  __builtin_memcpy(&u, &h, 2);
  return u;
}
// async global->LDS, 16B per lane. LDS dest is wave-uniform base + lane*16.
__device__ __forceinline__ void gload_lds16(const void* g, void* lds) {
  __builtin_amdgcn_global_load_lds(
      (const __attribute__((address_space(1))) u32*)g,
      (__attribute__((address_space(3))) u32*)lds, 16, 0, 0);
}

// ---------------------------------------------------------------------------
// Prep (merged): x fp32 -> bf16 xb  AND  weights -> bf16.
// Wh  [h][192][384]: rows = [Wq_h^T(64); Wk_h^T(64); Wv_h^T(64)].
// Wpt [n=384][c=384].
// Grid: 6144 blocks for x (8 elems/thread), 2304 blocks for weights.
// ---------------------------------------------------------------------------
__global__ __launch_bounds__(256) void prep_kernel(
    const float* __restrict__ x, const float* __restrict__ Wq,
    const float* __restrict__ Wk, const float* __restrict__ Wv,
    const float* __restrict__ Wp, u16* __restrict__ xb,
    u16* __restrict__ Wh, u16* __restrict__ Wpt) {
  const int bid = blockIdx.x;
  const int tid = threadIdx.x;
  if (bid < 6144) {  // x: 12,582,912 elems = 6144*256 chunks of 8
    const int i = bid * 256 + tid;
    const float4 f0 = ((const float4*)x)[i * 2];
    const float4 f1 = ((const float4*)x)[i * 2 + 1];
    bf16x8 pk;
    pk[0] = (short)f2b(f0.x); pk[1] = (short)f2b(f0.y);
    pk[2] = (short)f2b(f0.z); pk[3] = (short)f2b(f0.w);
    pk[4] = (short)f2b(f1.x); pk[5] = (short)f2b(f1.y);
    pk[6] = (short)f2b(f1.z); pk[7] = (short)f2b(f1.w);
    ((bf16x8*)xb)[i] = pk;
  } else {  // weights: 442368 + 147456 = 589824 = 2304*256
    const int idx = (bid - 6144) * 256 + tid;
    const int WHN = H_NUM * 192 * C_DIM;  // 442368
    if (idx < WHN) {
      int h = idx / (192 * C_DIM);
      int rem = idx % (192 * C_DIM);
      int r = rem / C_DIM, c = rem % C_DIM;
      int tz = r >> 6, d = r & 63;
      const float* W = (tz == 0) ? Wq : (tz == 1) ? Wk : Wv;
      Wh[idx] = f2b(W[((size_t)h * C_DIM + c) * HS + d]);
    } else {
      int j = idx - WHN;
      int n = j / C_DIM, c = j % C_DIM;
      Wpt[j] = f2b(Wp[c * C_DIM + n]);
    }
  }
}

// ---------------------------------------------------------------------------
// Kernel A: QKV projection. Block = 128 rows x ONE HEAD (N=192: q|k|v cols).
// 4 waves, wave tile 64x96 (acc 4x6). BK=64, async bf16 staging (m97-style).
// q,k -> [bh][t][d]; v -> LDS transpose -> vT [bh][d][t].
// LDS: As 16K + Bs 24K = 40960 B; Ts[64][136] aliases As.
// ---------------------------------------------------------------------------
__global__ __launch_bounds__(256) void qkv_gemm(
    const u16* __restrict__ xb, const u16* __restrict__ Wh,
    u16* __restrict__ q, u16* __restrict__ k, u16* __restrict__ vT) {
  __shared__ u16 smem[20480];  // 40960 B
  u16* As = smem;           // [128][64]
  u16* Bs = smem + 8192;    // [192][64]
  u16* Ts = smem;           // [64][136] v-transpose, aliases As (+Bs head)
  const int row0 = blockIdx.x * 128;
  const int h = blockIdx.y;
  const u16* a_rows = xb + (size_t)row0 * C_DIM;
  const u16* wbase = Wh + (size_t)h * 192 * C_DIM;

  const int tid = threadIdx.x;
  const int lane = tid & 63;
  const int w = tid >> 6;
  const int lr = lane >> 3;        // staging row within 8-row strip
  const int lkc = (lane & 7) * 8;  // staging col
  const int qd = lane >> 4;
  const int ln = lane & 15;
  const int wm = (w & 1) * 64;     // m-offset (64-row half)
  const int wn = (w >> 1) * 96;    // n-offset (96-col half)

  floatx4 acc[4][6];
#pragma unroll
  for (int i = 0; i < 4; ++i)
#pragma unroll
    for (int j = 0; j < 6; ++j) acc[i][j] = floatx4{0.f, 0.f, 0.f, 0.f};

  for (int kb = 0; kb < C_DIM / 64; ++kb) {
    const int k0 = kb * 64;
    __syncthreads();
    // A: 16 strips of 8 rows / 4 waves = 4 per wave
#pragma unroll
    for (int s = 0; s < 4; ++s) {
      const int rbase = (s * 4 + w) * 8;
      gload_lds16(a_rows + (size_t)(rbase + lr) * C_DIM + k0 + lkc,
                  As + rbase * 64);
    }
    // B: 24 strips of 8 rows / 4 waves = 6 per wave
#pragma unroll
    for (int s = 0; s < 6; ++s) {
      const int rbase = (s * 4 + w) * 8;
      gload_lds16(wbase + (size_t)(rbase + lr) * C_DIM + k0 + lkc,
                  Bs + rbase * 64);
    }
    __syncthreads();

#pragma unroll
    for (int kk = 0; kk < 2; ++kk) {
      bf16x8 af[4], bf[6];
#pragma unroll
      for (int mt = 0; mt < 4; ++mt)
        af[mt] = *(const bf16x8*)&As[(wm + mt * 16 + ln) * 64 + kk * 32 + qd * 8];
#pragma unroll
      for (int nt = 0; nt < 6; ++nt)
        bf[nt] = *(const bf16x8*)&Bs[(wn + nt * 16 + ln) * 64 + kk * 32 + qd * 8];
#pragma unroll
      for (int mt = 0; mt < 4; ++mt)
#pragma unroll
        for (int nt = 0; nt < 6; ++nt)
          acc[mt][nt] = __builtin_amdgcn_mfma_f32_16x16x32_bf16(
              af[mt], bf[nt], acc[mt][nt], 0, 0, 0);
    }
  }

  const int b = row0 >> 8;
  const int t0 = row0 & 255;
  __syncthreads();  // all fragment reads done; Ts (alias) safe to write

  // Epilogue: cols 0-63 = q, 64-127 = k, 128-191 = v (tz uniform per (w,nt)).
#pragma unroll
  for (int nt = 0; nt < 6; ++nt) {
    const int c0 = wn + nt * 16;
    const int tz = c0 >> 6;
    const int d = (c0 & 63) + ln;
#pragma unroll
    for (int mt = 0; mt < 4; ++mt) {
#pragma unroll
      for (int r = 0; r < 4; ++r) {
        const int tl = wm + mt * 16 + qd * 4 + r;  // 0..127
        const u16 val = f2b(acc[mt][nt][r]);
        if (tz == 0)
          q[(((size_t)b * H_NUM + h) * T_DIM + t0 + tl) * HS + d] = val;
        else if (tz == 1)
          k[(((size_t)b * H_NUM + h) * T_DIM + t0 + tl) * HS + d] = val;
        else
          Ts[d * 136 + tl] = val;  // stride 136 -> ~2-way banks (free)
      }
    }
  }
  __syncthreads();
  // vT copy-out, 16B coalesced: vt[d][t0..t0+128)
#pragma unroll
  for (int it = 0; it < 4; ++it) {
    const int idx = it * 256 + tid;
    const int d_l = idx >> 4, tc = idx & 15;
    *(uint4*)&vT[(((size_t)b * H_NUM + h) * HS + d_l) * T_DIM + t0 + tc * 8] =
        *(const uint4*)&Ts[d_l * 136 + tc * 8];
  }
}

// ---------------------------------------------------------------------------
// Kernel B: MFMA flash attention (round-3 verified, unchanged).
// ---------------------------------------------------------------------------
template <bool DIAG>
__device__ __forceinline__ void attn_chunk(int c, int mt, int lane, int ln,
                                           int qd, const bf16x8* qf,
                                           const u16* Kls, u16* Pw,
                                           const u16* vTg, floatx4* oacc,
                                           float* lsum) {
  floatx4 sacc[4];
#pragma unroll
  for (int st = 0; st < 4; ++st) {
    sacc[st] = floatx4{0.f, 0.f, 0.f, 0.f};
#pragma unroll
    for (int kc = 0; kc < 2; ++kc) {
      bf16x8 kf = *(const bf16x8*)&Kls[((c * 4 + st) * 2 + kc) * 512 + lane * 8];
      sacc[st] =
          __builtin_amdgcn_mfma_f32_16x16x32_bf16(qf[kc], kf, sacc[st], 0, 0, 0);
    }
  }
#pragma unroll
  for (int st = 0; st < 4; ++st) {
#pragma unroll
    for (int r = 0; r < 4; ++r) {
      const float sv = sacc[st][r] * 0.125f;
      float p = __expf(sv);
      if (DIAG) {
        const bool ok = (c * 64 + st * 16 + ln) <= (mt * 16 + qd * 4 + r);
        p = ok ? p : 0.f;
      }
      lsum[r] += p;
      Pw[(qd * 4 + r) * 72 + st * 16 + ln] = f2b(p);
    }
  }
#pragma unroll
  for (int kc2 = 0; kc2 < 2; ++kc2) {
    bf16x8 pf = *(const bf16x8*)&Pw[ln * 72 + kc2 * 32 + qd * 8];
#pragma unroll
    for (int dt = 0; dt < 4; ++dt) {
      bf16x8 vf = *(const bf16x8*)(vTg + (dt * 16 + ln) * 256 + c * 64 +
                                   kc2 * 32 + qd * 8);
      oacc[dt] =
          __builtin_amdgcn_mfma_f32_16x16x32_bf16(pf, vf, oacc[dt], 0, 0, 0);
    }
  }
}

__global__ __launch_bounds__(256) void attn_mfma(
    const u16* __restrict__ q, const u16* __restrict__ k,
    const u16* __restrict__ vT, u16* __restrict__ y) {
  __shared__ u16 Kls[32 * 512];   // 32 KB, fragment-major
  __shared__ u16 Pls[4 * 1152];   // per-wave P [16][72] bf16
  const int bh = blockIdx.x;
  const int b = bh / H_NUM, h = bh % H_NUM;
  const int tid = threadIdx.x, lane = tid & 63, w = tid >> 6;
  const int ln = lane & 15, qd = lane >> 4;
  const u16* qg = q + (size_t)bh * (T_DIM * HS);
  const u16* kg = k + (size_t)bh * (T_DIM * HS);
  const u16* vTg = vT + (size_t)bh * (HS * T_DIM);
  u16* Pw = Pls + w * 1152;

#pragma unroll
  for (int ff = 0; ff < 8; ++ff) {
    const int fid = w * 8 + ff;
    const int S16 = fid >> 1, kc = fid & 1;
    gload_lds16(kg + (S16 * 16 + ln) * 64 + kc * 32 + qd * 8, &Kls[fid * 512]);
  }
  __syncthreads();

#pragma unroll
  for (int i = 0; i < 4; ++i) {
    const int mt = i * 4 + w;
    bf16x8 qf[2];
#pragma unroll
    for (int kc = 0; kc < 2; ++kc)
      qf[kc] = *(const bf16x8*)(qg + (mt * 16 + ln) * 64 + kc * 32 + qd * 8);

    floatx4 oacc[4];
    float lsum[4];
#pragma unroll
    for (int dt = 0; dt < 4; ++dt) oacc[dt] = floatx4{0.f, 0.f, 0.f, 0.f};
#pragma unroll
    for (int r = 0; r < 4; ++r) lsum[r] = 0.f;

    const int cmax = mt >> 2;
    for (int c = 0; c < cmax; ++c)
      attn_chunk<false>(c, mt, lane, ln, qd, qf, Kls, Pw, vTg, oacc, lsum);
    attn_chunk<true>(cmax, mt, lane, ln, qd, qf, Kls, Pw, vTg, oacc, lsum);

#pragma unroll
    for (int off = 1; off < 16; off <<= 1)
#pragma unroll
      for (int r = 0; r < 4; ++r) lsum[r] += __shfl_xor(lsum[r], off);

#pragma unroll
    for (int r = 0; r < 4; ++r) {
      const float inv = 1.f / lsum[r];
      const int t = mt * 16 + qd * 4 + r;
      u16* yo = y + ((size_t)b * T_DIM + t) * C_DIM + h * HS;
#pragma unroll
      for (int dt = 0; dt < 4; ++dt) yo[dt * 16 + ln] = f2b(oacc[dt][r] * inv);
    }
  }
}

// ---------------------------------------------------------------------------
// Kernel C: output projection via MFMA (round-3 verified, unchanged).
// ---------------------------------------------------------------------------
__global__ __launch_bounds__(256) void proj_gemm(
    const u16* __restrict__ yb, const u16* __restrict__ Wpt,
    const float* __restrict__ bp, float* __restrict__ out) {
  __shared__ u16 As[128 * 64];
  __shared__ u16 Bs[128 * 64];
  const int row0 = blockIdx.x * 128;
  const int n0 = blockIdx.y * 128;
  const u16* a_rows = yb + (size_t)row0 * C_DIM;
  const u16* bt_rows = Wpt + (size_t)n0 * C_DIM;

  const int tid = threadIdx.x;
  const int lane = tid & 63;
  const int w = tid >> 6;
  const int lr = lane >> 3;
  const int lkc = (lane & 7) * 8;
  const int qd = lane >> 4;
  const int ln = lane & 15;
  const int mw = (w >> 1) * 64;
  const int nw = (w & 1) * 64;

  floatx4 acc[4][4];
#pragma unroll
  for (int i = 0; i < 4; ++i)
#pragma unroll
    for (int j = 0; j < 4; ++j) acc[i][j] = floatx4{0.f, 0.f, 0.f, 0.f};

  for (int kb = 0; kb < C_DIM / 64; ++kb) {
    const int k0 = kb * 64;
    __syncthreads();
#pragma unroll
    for (int s = 0; s < 4; ++s) {
      const int rbase = (s * 4 + w) * 8;
      gload_lds16(a_rows + (size_t)(rbase + lr) * C_DIM + k0 + lkc,
                  As + rbase * 64);
      gload_lds16(bt_rows + (size_t)(rbase + lr) * C_DIM + k0 + lkc,
                  Bs + rbase * 64);
    }
    __syncthreads();

#pragma unroll
    for (int kk = 0; kk < 2; ++kk) {
      bf16x8 af[4], bf[4];
#pragma unroll
      for (int mt = 0; mt < 4; ++mt)
        af[mt] = *(const bf16x8*)&As[(mw + mt * 16 + ln) * 64 + kk * 32 + qd * 8];
#pragma unroll
      for (int nt = 0; nt < 4; ++nt)
        bf[nt] = *(const bf16x8*)&Bs[(nw + nt * 16 + ln) * 64 + kk * 32 + qd * 8];
#pragma unroll
      for (int mt = 0; mt < 4; ++mt)
#pragma unroll
        for (int nt = 0; nt < 4; ++nt)
          acc[mt][nt] = __builtin_amdgcn_mfma_f32_16x16x32_bf16(
              af[mt], bf[nt], acc[mt][nt], 0, 0, 0);
    }
  }

#pragma unroll
  for (int nt = 0; nt < 4; ++nt) {
    const int col = n0 + nw + nt * 16 + ln;
    const float bias = bp[col];
#pragma unroll
    for (int mt = 0; mt < 4; ++mt) {
#pragma unroll
      for (int r = 0; r < 4; ++r) {
        const int grow = row0 + mw + mt * 16 + qd * 4 + r;
        out[(size_t)grow * C_DIM + col] = acc[mt][nt][r] + bias;
      }
    }
  }
}

// ---------------------------------------------------------------------------
extern "C" void kernel_launch(void* const* d_in, const int* in_sizes, int n_in,
                              void* d_out, int out_size, void* d_ws, size_t ws_size,
                              hipStream_t stream) {
  const float* x  = (const float*)d_in[0];
  const float* Wq = (const float*)d_in[1];
  const float* Wk = (const float*)d_in[2];
  const float* Wv = (const float*)d_in[3];
  const float* Wp = (const float*)d_in[4];
  const float* bp = (const float*)d_in[5];
  float* out = (float*)d_out;

  const size_t n_x = (size_t)NROWS * C_DIM;                     // 12,582,912
  const size_t qkv_elems = (size_t)B_DIM * H_NUM * T_DIM * HS;  // 12,582,912

  u16* Wh  = (u16*)d_ws;                    // [6][192][384]
  u16* Wpt = Wh + (size_t)H_NUM * 192 * C_DIM;
  u16* xb  = Wpt + C_DIM * C_DIM;           // [32768][384] bf16
  u16* q   = xb + n_x;                      // [bh][t][d]
  u16* k   = q + qkv_elems;                 // [bh][t][d]
  u16* vT  = k + qkv_elems;                 // [bh][d][t]
  u16* y   = xb;  // alias: xb dead after qkv_gemm
  // ws: 1.2 + 25.2 + 75.5 = ~102 MB

  prep_kernel<<<6144 + 2304, 256, 0, stream>>>(x, Wq, Wk, Wv, Wp, xb, Wh, Wpt);
  qkv_gemm<<<dim3(NROWS / 128, H_NUM), 256, 0, stream>>>(xb, Wh, q, k, vT);
  attn_mfma<<<B_DIM * H_NUM, 256, 0, stream>>>(q, k, vT, y);
  proj_gemm<<<dim3(NROWS / 128, 3), 256, 0, stream>>>(y, Wpt, bp, out);
}